// Round 2
// baseline (93.082 us; speedup 1.0000x reference)
//
#include <hip/hip_runtime.h>
#include <hip/hip_bf16.h>
#include <stdint.h>

namespace {

constexpr int Hh    = 16;
constexpr int LL    = 4096;
constexpr int DD    = 64;
constexpr int BH    = 4 * 16;        // B*H
constexpr int CHUNK = 256;           // rows per block
constexpr int NCH   = LL / CHUNK;    // 16 chunks per (b,h)
constexpr int RECF  = 128;           // floats per ws record (64 k-sums + 64 kv-sums)
constexpr int CREC  = 17;            // records per chunk: [0]=total, [1+team]=excl prefix
constexpr float EPS = 1e-6f;

__device__ __forceinline__ float elu1(float x) {
    return x > 0.0f ? x + 1.0f : __expf(x);
}

// --- cross-lane helpers (16-lane team butterfly sum) ---
template<int CTRL>
__device__ __forceinline__ float dpp_xor_add(float x) {
    int yi = __builtin_amdgcn_update_dpp(0, __float_as_int(x), CTRL, 0xF, 0xF, true);
    return x + __int_as_float(yi);
}
template<int IMM>
__device__ __forceinline__ float swz_xor_add(float x) {
    int yi = __builtin_amdgcn_ds_swizzle(__float_as_int(x), IMM);
    return x + __int_as_float(yi);
}
__device__ __forceinline__ float team_sum16(float x) {
    x = dpp_xor_add<0xB1>(x);      // quad_perm [1,0,3,2]  : xor 1
    x = dpp_xor_add<0x4E>(x);      // quad_perm [2,3,0,1]  : xor 2
    x = swz_xor_add<0x101F>(x);    // ds_swizzle xor 4
    x = swz_xor_add<0x201F>(x);    // ds_swizzle xor 8
    return x;
}

// --- async global->LDS 16B (wave-uniform LDS base + lane*16) ---
typedef const __attribute__((address_space(1))) void* as1_t;
typedef __attribute__((address_space(3))) void* as3_t;
__device__ __forceinline__ void gload16(const void* g, void* l) {
    __builtin_amdgcn_global_load_lds((as1_t)g, (as3_t)l, 16, 0, 0);
}

// ============================================================================
// Pass 1: per-team (16-row) subchunk totals, scanned in-block into
//   ws[bh][ch][0]      = chunk total        (128 floats: 64 k | 64 kv)
//   ws[bh][ch][1+team] = exclusive prefix within chunk before this team
// ============================================================================
__global__ __launch_bounds__(256) void la_pass1(
    const float* __restrict__ kp, const float* __restrict__ vp,
    const float* __restrict__ maskp, float* __restrict__ ws)
{
    const int blk  = blockIdx.x;
    const int bh   = blk >> 4;          // / NCH
    const int ch   = blk & (NCH - 1);
    const int b    = bh >> 4;           // / Hh
    const int t    = threadIdx.x;
    const int qd   = t & 15;
    const int team = t >> 4;

    const long base  = ((long)bh * LL + (long)ch * CHUNK) * DD;
    const long rbase = base + (long)team * 16 * DD + qd * 4;
    const float* mrow = maskp + (long)b * LL + (long)ch * CHUNK + team * 16;

    float sk0=0.f,sk1=0.f,sk2=0.f,sk3=0.f;
    float sv0=0.f,sv1=0.f,sv2=0.f,sv3=0.f;

    #pragma unroll
    for (int r = 0; r < 16; ++r) {
        const float4 k4 = *(const float4*)(kp + rbase + r * DD);
        const float4 v4 = *(const float4*)(vp + rbase + r * DD);
        const float  m  = mrow[r];
        const float kf0 = elu1(k4.x) * m;
        const float kf1 = elu1(k4.y) * m;
        const float kf2 = elu1(k4.z) * m;
        const float kf3 = elu1(k4.w) * m;
        sk0 += kf0;              sk1 += kf1;
        sk2 += kf2;              sk3 += kf3;
        sv0 += kf0 * (v4.x * m); sv1 += kf1 * (v4.y * m);
        sv2 += kf2 * (v4.z * m); sv3 += kf3 * (v4.w * m);
    }

    __shared__ float red[16][RECF];
    red[team][qd*4+0] = sk0; red[team][qd*4+1] = sk1;
    red[team][qd*4+2] = sk2; red[team][qd*4+3] = sk3;
    red[team][64+qd*4+0] = sv0; red[team][64+qd*4+1] = sv1;
    red[team][64+qd*4+2] = sv2; red[team][64+qd*4+3] = sv3;
    __syncthreads();

    if (t < RECF) {
        float acc = 0.f;
        float* wbase = ws + ((long)bh * NCH + ch) * (CREC * RECF);
        #pragma unroll
        for (int i = 0; i < 16; ++i) {
            wbase[(1 + i) * RECF + t] = acc;   // exclusive prefix before team i
            acc += red[i][t];
        }
        wbase[t] = acc;                        // record 0: chunk total
    }
}

// ============================================================================
// Pass 2: carry from ws + serial 16-row scan per team, LDS-staged streams.
// Wave-private double-buffered staging: 2 rows/team/iter, k+v+q = 6 KB/buffer.
// ============================================================================
__global__ __launch_bounds__(256) void la_pass2(
    const float* __restrict__ qp, const float* __restrict__ kp,
    const float* __restrict__ vp, const float* __restrict__ maskp,
    const float* __restrict__ ws, float* __restrict__ outp)
{
    const int blk  = blockIdx.x;
    const int bh   = blk >> 4;
    const int ch   = blk & (NCH - 1);
    const int b    = bh >> 4;
    const int t    = threadIdx.x;
    const int qd   = t & 15;
    const int team = t >> 4;
    const int wave = t >> 6;
    const int ln   = t & 63;

    const long base  = ((long)bh * LL + (long)ch * CHUNK) * DD;
    const long lbase = base + (long)team * 16 * DD + qd * 4;  // this lane's slot, row 0
    const float* mrow = maskp + (long)b * LL + (long)ch * CHUNK + team * 16;

    // [wave][buf][(2*stream + rowpair) * 256 + lane*4]  (floats), 16B-aligned
    __shared__ __align__(16) float sbuf[4][2][6 * 256];

    const float* streams[3] = { kp, vp, qp };

    // ---- issue iteration 0 (rows 0,1) into buf 0, before the carry loop ----
    #pragma unroll
    for (int s = 0; s < 3; ++s)
        #pragma unroll
        for (int j = 0; j < 2; ++j)
            gload16(streams[s] + lbase + (long)j * DD,
                    &sbuf[wave][0][(2 * s + j) * 256]);

    // ---- carry: sum of preceding chunk totals + own subchunk prefix ----
    float rk0=0.f,rk1=0.f,rk2=0.f,rk3=0.f;
    float rv0=0.f,rv1=0.f,rv2=0.f,rv3=0.f;
    const float* wb = ws + (long)bh * NCH * (CREC * RECF);
    for (int c = 0; c < ch; ++c) {
        const float* rec = wb + (long)c * (CREC * RECF);
        const float4 a  = *(const float4*)(rec + qd * 4);
        const float4 bb = *(const float4*)(rec + 64 + qd * 4);
        rk0 += a.x;  rk1 += a.y;  rk2 += a.z;  rk3 += a.w;
        rv0 += bb.x; rv1 += bb.y; rv2 += bb.z; rv3 += bb.w;
    }
    {
        const float* rec = wb + (long)ch * (CREC * RECF) + (1 + team) * RECF;
        const float4 a  = *(const float4*)(rec + qd * 4);
        const float4 bb = *(const float4*)(rec + 64 + qd * 4);
        rk0 += a.x;  rk1 += a.y;  rk2 += a.z;  rk3 += a.w;
        rv0 += bb.x; rv1 += bb.y; rv2 += bb.z; rv3 += bb.w;
    }

    // ---- main: 8 iterations x 2 rows, double-buffered wave-private staging ----
    #pragma unroll
    for (int i = 0; i < 8; ++i) {
        const int buf = i & 1;
        // all outstanding DMA (this iter's buffer) complete; conservative but safe
        asm volatile("s_waitcnt vmcnt(0)" ::: "memory");
        if (i < 7) {
            const int r0n = 2 * (i + 1);
            #pragma unroll
            for (int s = 0; s < 3; ++s)
                #pragma unroll
                for (int j = 0; j < 2; ++j)
                    gload16(streams[s] + lbase + (long)(r0n + j) * DD,
                            &sbuf[wave][buf ^ 1][(2 * s + j) * 256]);
        }
        #pragma unroll
        for (int j = 0; j < 2; ++j) {
            const int row = 2 * i + j;
            const float4 k4 = *(const float4*)&sbuf[wave][buf][(0 + j) * 256 + ln * 4];
            const float4 v4 = *(const float4*)&sbuf[wave][buf][(2 + j) * 256 + ln * 4];
            const float4 q4 = *(const float4*)&sbuf[wave][buf][(4 + j) * 256 + ln * 4];
            const float  m  = mrow[row];

            const float kf0 = elu1(k4.x) * m;
            const float kf1 = elu1(k4.y) * m;
            const float kf2 = elu1(k4.z) * m;
            const float kf3 = elu1(k4.w) * m;
            rk0 += kf0;              rk1 += kf1;
            rk2 += kf2;              rk3 += kf3;
            rv0 += kf0 * (v4.x * m); rv1 += kf1 * (v4.y * m);
            rv2 += kf2 * (v4.z * m); rv3 += kf3 * (v4.w * m);

            const float qf0 = elu1(q4.x);
            const float qf1 = elu1(q4.y);
            const float qf2 = elu1(q4.z);
            const float qf3 = elu1(q4.w);

            float pz = qf0*rk0 + qf1*rk1 + qf2*rk2 + qf3*rk3;
            pz = team_sum16(pz);

            const float z   = (pz + EPS) * m;
            const float inv = __builtin_amdgcn_rcpf(z);

            float4 o;
            o.x = qf0 * rv0 * inv;
            o.y = qf1 * rv1 * inv;
            o.z = qf2 * rv2 * inv;
            o.w = qf3 * rv3 * inv;
            *(float4*)(outp + lbase + (long)row * DD) = o;
        }
    }
}

} // namespace

extern "C" void kernel_launch(void* const* d_in, const int* in_sizes, int n_in,
                              void* d_out, int out_size, void* d_ws, size_t ws_size,
                              hipStream_t stream) {
    const float* q    = (const float*)d_in[0];
    const float* k    = (const float*)d_in[1];
    const float* v    = (const float*)d_in[2];
    const float* mask = (const float*)d_in[3];
    float* out = (float*)d_out;
    float* ws  = (float*)d_ws;   // needs BH*NCH*17*128 floats = 8.5 MiB

    dim3 grid(BH * NCH);
    dim3 block(256);
    la_pass1<<<grid, block, 0, stream>>>(k, v, mask, ws);
    la_pass2<<<grid, block, 0, stream>>>(q, k, v, mask, ws, out);
}

// Round 4
// 87.058 us; speedup vs baseline: 1.0692x; 1.0692x over previous
//
#include <hip/hip_runtime.h>
#include <hip/hip_bf16.h>

namespace {

constexpr int Hh    = 16;
constexpr int LL    = 4096;
constexpr int DD    = 64;
constexpr int BH    = 64;            // B*H
constexpr int CHUNK = 128;           // rows per block
constexpr int NCH   = LL / CHUNK;    // 32 chunks per (b,h)
constexpr int RPT   = 8;             // rows per 16-lane team
constexpr int RECF  = 128;           // floats per ws record (64 k-sums | 64 kv-sums)
constexpr float EPS = 1e-6f;

typedef __attribute__((ext_vector_type(4))) float f32x4;

__device__ __forceinline__ float elu1(float x) {
    return x > 0.0f ? x + 1.0f : __expf(x);
}

// --- 16-lane team butterfly sum (teams are 16-lane aligned within the wave) ---
template<int CTRL>
__device__ __forceinline__ float dpp_xor_add(float x) {
    int yi = __builtin_amdgcn_update_dpp(0, __float_as_int(x), CTRL, 0xF, 0xF, true);
    return x + __int_as_float(yi);
}
template<int IMM>
__device__ __forceinline__ float swz_xor_add(float x) {
    int yi = __builtin_amdgcn_ds_swizzle(__float_as_int(x), IMM);
    return x + __int_as_float(yi);
}
__device__ __forceinline__ float team_sum16(float x) {
    x = dpp_xor_add<0xB1>(x);      // quad_perm xor 1
    x = dpp_xor_add<0x4E>(x);      // quad_perm xor 2
    x = swz_xor_add<0x101F>(x);    // ds_swizzle xor 4
    x = swz_xor_add<0x201F>(x);    // ds_swizzle xor 8
    return x;
}

__device__ __forceinline__ float4 f4add(float4 a, float4 b) {
    return make_float4(a.x + b.x, a.y + b.y, a.z + b.z, a.w + b.w);
}

// ============================================================================
// Pass 1: per-chunk (128-row) totals of kf and kf*vm -> ws[bh][ch][128]
// ============================================================================
__global__ __launch_bounds__(256) void la_pass1(
    const float* __restrict__ kp, const float* __restrict__ vp,
    const float* __restrict__ maskp, float* __restrict__ ws)
{
    const int blk  = blockIdx.x;
    const int bh   = blk >> 5;          // / NCH
    const int ch   = blk & (NCH - 1);
    const int b    = bh >> 4;           // / Hh
    const int t    = threadIdx.x;
    const int qd   = t & 15;
    const int team = t >> 4;

    const long base  = ((long)bh * LL + (long)ch * CHUNK) * DD;
    const long rbase = base + (long)team * RPT * DD + qd * 4;
    const float* mrow = maskp + (long)b * LL + (long)ch * CHUNK + team * RPT;

    float4 sk = make_float4(0.f, 0.f, 0.f, 0.f);
    float4 sv = make_float4(0.f, 0.f, 0.f, 0.f);

    #pragma unroll
    for (int r = 0; r < RPT; ++r) {
        const float4 k4 = *(const float4*)(kp + rbase + (long)r * DD);
        const float4 v4 = *(const float4*)(vp + rbase + (long)r * DD);
        const float  m  = mrow[r];
        const float kf0 = elu1(k4.x) * m;
        const float kf1 = elu1(k4.y) * m;
        const float kf2 = elu1(k4.z) * m;
        const float kf3 = elu1(k4.w) * m;
        sk.x += kf0;              sk.y += kf1;
        sk.z += kf2;              sk.w += kf3;
        sv.x += kf0 * (v4.x * m); sv.y += kf1 * (v4.y * m);
        sv.z += kf2 * (v4.z * m); sv.w += kf3 * (v4.w * m);
    }

    __shared__ float red[16][RECF];
    red[team][qd*4+0] = sk.x; red[team][qd*4+1] = sk.y;
    red[team][qd*4+2] = sk.z; red[team][qd*4+3] = sk.w;
    red[team][64+qd*4+0] = sv.x; red[team][64+qd*4+1] = sv.y;
    red[team][64+qd*4+2] = sv.z; red[team][64+qd*4+3] = sv.w;
    __syncthreads();

    if (t < RECF) {
        float acc = 0.f;
        #pragma unroll
        for (int i = 0; i < 16; ++i) acc += red[i][t];
        ws[((long)bh * NCH + ch) * RECF + t] = acc;
    }
}

// ============================================================================
// Pass 2: bulk register-tile load (8 rows x {k,v,q} per team), carry from ws,
// in-block team scan via LDS, serial 8-row scan + output.
// ============================================================================
__global__ __launch_bounds__(256) void la_pass2(
    const float* __restrict__ qp, const float* __restrict__ kp,
    const float* __restrict__ vp, const float* __restrict__ maskp,
    const float* __restrict__ ws, float* __restrict__ outp)
{
    const int blk  = blockIdx.x;
    const int bh   = blk >> 5;
    const int ch   = blk & (NCH - 1);
    const int b    = bh >> 4;
    const int t    = threadIdx.x;
    const int qd   = t & 15;
    const int team = t >> 4;

    const long base  = ((long)bh * LL + (long)ch * CHUNK) * DD;
    const long rbase = base + (long)team * RPT * DD + qd * 4;
    const float* mrow = maskp + (long)b * LL + (long)ch * CHUNK + team * RPT;

    // ---- bulk load the whole team tile into registers (24 float4 in flight) ----
    float4 kb[RPT], vb[RPT], qb[RPT];
    #pragma unroll
    for (int r = 0; r < RPT; ++r) {
        kb[r] = *(const float4*)(kp + rbase + (long)r * DD);
        vb[r] = *(const float4*)(vp + rbase + (long)r * DD);
        qb[r] = *(const float4*)(qp + rbase + (long)r * DD);
    }
    float mv[RPT];
    #pragma unroll
    for (int r = 0; r < RPT; ++r) mv[r] = mrow[r];

    // ---- carry: sum of preceding chunk totals (L2-hot, overlaps tile loads) ----
    float4 ck = make_float4(0.f, 0.f, 0.f, 0.f);
    float4 cv = make_float4(0.f, 0.f, 0.f, 0.f);
    const float* wb = ws + (long)bh * NCH * RECF;
    for (int c = 0; c < ch; ++c) {
        const float* rec = wb + (long)c * RECF;
        ck = f4add(ck, *(const float4*)(rec + qd * 4));
        cv = f4add(cv, *(const float4*)(rec + 64 + qd * 4));
    }

    // ---- transform in registers: kf = elu1(k)*m, kv = kf*(v*m) ----
    float4 kf[RPT], kv[RPT];
    #pragma unroll
    for (int r = 0; r < RPT; ++r) {
        const float m = mv[r];
        float4 f;
        f.x = elu1(kb[r].x) * m; f.y = elu1(kb[r].y) * m;
        f.z = elu1(kb[r].z) * m; f.w = elu1(kb[r].w) * m;
        kf[r] = f;
        float4 g;
        g.x = f.x * (vb[r].x * m); g.y = f.y * (vb[r].y * m);
        g.z = f.z * (vb[r].z * m); g.w = f.w * (vb[r].w * m);
        kv[r] = g;
    }

    // ---- team totals (registers only) ----
    float4 tk = make_float4(0.f, 0.f, 0.f, 0.f);
    float4 tv = make_float4(0.f, 0.f, 0.f, 0.f);
    #pragma unroll
    for (int r = 0; r < RPT; ++r) { tk = f4add(tk, kf[r]); tv = f4add(tv, kv[r]); }

    // ---- in-block exclusive scan over the 16 teams ----
    __shared__ float red[16][RECF];
    __shared__ float pre[16][RECF];
    red[team][qd*4+0] = tk.x; red[team][qd*4+1] = tk.y;
    red[team][qd*4+2] = tk.z; red[team][qd*4+3] = tk.w;
    red[team][64+qd*4+0] = tv.x; red[team][64+qd*4+1] = tv.y;
    red[team][64+qd*4+2] = tv.z; red[team][64+qd*4+3] = tv.w;
    __syncthreads();
    if (t < RECF) {
        float acc = 0.f;
        #pragma unroll
        for (int i = 0; i < 16; ++i) { pre[i][t] = acc; acc += red[i][t]; }
    }
    __syncthreads();

    float4 rk, rv;
    rk.x = ck.x + pre[team][qd*4+0]; rk.y = ck.y + pre[team][qd*4+1];
    rk.z = ck.z + pre[team][qd*4+2]; rk.w = ck.w + pre[team][qd*4+3];
    rv.x = cv.x + pre[team][64+qd*4+0]; rv.y = cv.y + pre[team][64+qd*4+1];
    rv.z = cv.z + pre[team][64+qd*4+2]; rv.w = cv.w + pre[team][64+qd*4+3];

    // ---- serial scan over the team's 8 rows, emit output ----
    #pragma unroll
    for (int r = 0; r < RPT; ++r) {
        rk = f4add(rk, kf[r]);
        rv = f4add(rv, kv[r]);

        float4 qf;
        qf.x = elu1(qb[r].x); qf.y = elu1(qb[r].y);
        qf.z = elu1(qb[r].z); qf.w = elu1(qb[r].w);

        float pz = qf.x*rk.x + qf.y*rk.y + qf.z*rk.z + qf.w*rk.w;
        pz = team_sum16(pz);

        const float z   = (pz + EPS) * mv[r];
        const float inv = __builtin_amdgcn_rcpf(z);

        f32x4 o;
        o.x = qf.x * rv.x * inv;
        o.y = qf.y * rv.y * inv;
        o.z = qf.z * rv.z * inv;
        o.w = qf.w * rv.w * inv;
        __builtin_nontemporal_store(o, (f32x4*)(outp + rbase + (long)r * DD));
    }
}

} // namespace

extern "C" void kernel_launch(void* const* d_in, const int* in_sizes, int n_in,
                              void* d_out, int out_size, void* d_ws, size_t ws_size,
                              hipStream_t stream) {
    const float* q    = (const float*)d_in[0];
    const float* k    = (const float*)d_in[1];
    const float* v    = (const float*)d_in[2];
    const float* mask = (const float*)d_in[3];
    float* out = (float*)d_out;
    float* ws  = (float*)d_ws;   // needs BH*NCH*RECF floats = 1 MiB

    dim3 grid(BH * NCH);
    dim3 block(256);
    la_pass1<<<grid, block, 0, stream>>>(k, v, mask, ws);
    la_pass2<<<grid, block, 0, stream>>>(q, k, v, mask, ws, out);
}